// Round 11
// baseline (194.817 us; speedup 1.0000x reference)
//
#include <hip/hip_runtime.h>
#include <math.h>

#define Bb   48
#define Ww   100
#define Nn   1000
#define EMB  128
#define Hh   8
#define LL   101     // depot + 100 neighbors
#define LOCALK 100
#define TPB  128
#define PPB  2       // problems (waves) per block in kernel A

typedef float f4v __attribute__((ext_vector_type(4)));

// ---- workspace layout (float offsets)
#define WS_A     0       // [8][128]  a_h = (Wk q_h)/4
#define WS_PE    1024    // [101][128] pos-enc f32
#define WS_AC    13952   // [3][8] A_i[h] then [8] C[h]
#define WS_WVI   13984   // [4][128]  w_i·Wv[:,hd] (i=3 -> b)
#define WS_PEA   14496   // [8][101]  pe[l]·a_h
#define WS_PVT   15304   // f16 [101][128]  PVT[l][hd] = pe[l]·Wv[:,hd]
#define WS_GPT   21768   // f16 [128][104]  GPT[hd][l] = Wcw[hd]·pe[l], l>=101 -> 0
#define WS_WCW   28424   // f32 [4][128]  Wcw·w_i  (i=3 -> b)
#define WS_CB    28936   // f32 [4]       Wcb·w_i
#define WS_CBPE  28940   // f32 [104]     Wcb·pe[l]
// end 29044 floats = 116 KB

// ---- kernel A per-problem LDS arena (bytes), regions time-multiplexed
#define AR_SIZE 7360
#define AR_LIST 4288     // u64[100]
#define AR_SEL  5088     // i32[104]  (node | 0x4000 inf-flag; pad 101..103 = 0)
#define AR_PERM 5504     // u8[104]
#define AR_SMK  5616     // f32[101]
#define AR_F3   6032     // f32[304]  (pad [303] = 0)
#define AR_COEF 7248     // f32[24]

// staging layout inside each out row (f32 slots):
//  [0..415]   attn f16[8][104]
//  [416..567] feat f16[304]
//  [568..619] sel  u16[104]
//  [620..643] coef f32[24]

#define WSYNC() do { __builtin_amdgcn_wave_barrier(); asm volatile("" ::: "memory"); } while (0)

__device__ __forceinline__ unsigned f2key(float x) {
    unsigned u = __float_as_uint(x);
    return (u & 0x80000000u) ? ~u : (u | 0x80000000u);
}
__device__ __forceinline__ float key2f(unsigned k) {
    unsigned u = (k & 0x80000000u) ? (k & 0x7fffffffu) : ~k;
    return __uint_as_float(u);
}
__device__ __forceinline__ unsigned short f2hbits(float x) {
    union { _Float16 h; unsigned short u; } cv;
    cv.h = (_Float16)x;
    return cv.u;
}

// ---- S1: q, a, A/C (block 0); pe + WVi (blocks 1..)
__global__ void setup1(const float* __restrict__ cur, const float* __restrict__ Wq,
                       const float* __restrict__ Wk, const float* __restrict__ iw,
                       const float* __restrict__ ib, const float* __restrict__ Wv,
                       float* __restrict__ ws) {
    const int t = threadIdx.x, b = blockIdx.x;
    if (b == 0) {
        __shared__ float qs[EMB];
        __shared__ float as_[Hh * EMB];
        if (t < EMB) {
            float acc = 0.f;
            for (int e = 0; e < EMB; ++e) acc += cur[e] * Wq[e * EMB + t];
            qs[t] = acc;
        }
        __syncthreads();
        for (int i = t; i < Hh * EMB; i += 256) {
            int h = i >> 7, e = i & 127;
            float acc = 0.f;
            for (int d = 0; d < 16; ++d) acc += Wk[e * EMB + h * 16 + d] * qs[h * 16 + d];
            acc *= 0.25f;
            as_[i] = acc; ws[WS_A + i] = acc;
        }
        __syncthreads();
        if (t < 32) {
            int i = t >> 3, h = t & 7;
            const float* src = (i == 0) ? iw : (i == 1) ? iw + EMB : (i == 2) ? iw + 2 * EMB : ib;
            float acc = 0.f;
            for (int e = 0; e < EMB; ++e) acc += src[e] * as_[h * EMB + e];
            ws[WS_AC + t] = acc;
        }
    } else {
        int base = (b - 1) * 256 + t;
        const float kneg = -0.14619587891040738f;  // -ln(10000)/63
        if (base < LL * EMB) {
            int l = base >> 7, c = base & 127, ic = c & 63;
            float inv = expf((float)ic * kneg);
            float v = (float)l * inv;
            ws[WS_PE + base] = (c < 64) ? sinf(v) : cosf(v);
        } else if (base < LL * EMB + 512) {
            int j = base - LL * EMB;
            int iv = j >> 7, hd = j & 127;
            const float* src = (iv == 0) ? iw : (iv == 1) ? iw + EMB : (iv == 2) ? iw + 2 * EMB : ib;
            float acc = 0.f;
            for (int e = 0; e < EMB; ++e) acc += src[e] * Wv[e * EMB + hd];
            ws[WS_WVI + j] = acc;
        }
    }
}

// ---- S2: PVT f16, GPT f16, PEA, WCW, cb, cbpe  (reads ws PE/A from setup1)
__global__ void setup2(const float* __restrict__ Wv, const float* __restrict__ Wcw,
                       const float* __restrict__ Wcb, const float* __restrict__ iw,
                       const float* __restrict__ ib, float* __restrict__ ws) {
    int idx = blockIdx.x * 256 + threadIdx.x;
    if (idx < 12928) {                               // PVT[l][hd]
        int l = idx >> 7, hd = idx & 127;
        const float* pr = ws + WS_PE + l * EMB;
        float acc = 0.f;
        for (int e = 0; e < EMB; ++e) acc += pr[e] * Wv[e * EMB + hd];
        ((_Float16*)(ws + WS_PVT))[idx] = (_Float16)acc;
    } else if (idx < 12928 + 13312) {                // GPT[hd][l]
        int j = idx - 12928;
        int hd = j / 104, l = j - hd * 104;
        float acc = 0.f;
        if (l < LL) {
            const float* wr = Wcw + hd * EMB;
            const float* pr = ws + WS_PE + l * EMB;
            for (int e = 0; e < EMB; ++e) acc += wr[e] * pr[e];
        }
        ((_Float16*)(ws + WS_GPT))[j] = (_Float16)acc;
    } else if (idx < 26240 + 808) {                  // PEA[h][l]
        int j = idx - 26240;
        int h = j / LL, l = j - h * LL;
        const float* pr = ws + WS_PE + l * EMB;
        const float* ar = ws + WS_A + h * EMB;
        float acc = 0.f;
        for (int e = 0; e < EMB; ++e) acc += pr[e] * ar[e];
        ws[WS_PEA + j] = acc;
    } else if (idx < 27048 + 512) {                  // WCW[i][hd]
        int j = idx - 27048;
        int i = j >> 7, hd = j & 127;
        const float* src = (i == 0) ? iw : (i == 1) ? iw + EMB : (i == 2) ? iw + 2 * EMB : ib;
        const float* wr = Wcw + hd * EMB;
        float acc = 0.f;
        for (int e = 0; e < EMB; ++e) acc += wr[e] * src[e];
        ws[WS_WCW + j] = acc;
    } else if (idx < 27560 + 4) {                    // cb[i]
        int i = idx - 27560;
        const float* src = (i == 0) ? iw : (i == 1) ? iw + EMB : (i == 2) ? iw + 2 * EMB : ib;
        float acc = 0.f;
        for (int e = 0; e < EMB; ++e) acc += Wcb[e] * src[e];
        ws[WS_CB + i] = acc;
    } else if (idx < 27564 + 104) {                  // cbpe[l]
        int l = idx - 27564;
        float acc = 0.f;
        if (l < LL) {
            const float* pr = ws + WS_PE + l * EMB;
            for (int e = 0; e < EMB; ++e) acc += Wcb[e] * pr[e];
        }
        ws[WS_CBPE + l] = acc;
    }
}

// ================= Kernel A: select + features + attn + coef -> staging =================
__global__ __launch_bounds__(TPB, 5) void kernelA(
    const float* __restrict__ dist,
    const float* __restrict__ xy,
    const float* __restrict__ ndem,
    const float* __restrict__ ninf,
    const float* __restrict__ ws,
    float* __restrict__ out) {

    __shared__ __align__(16) char smem[PPB][AR_SIZE];
    __shared__ __align__(16) float sPEA[Hh * LL + 32];

    const int tid  = threadIdx.x;
    const int w    = tid >> 6;
    const int lane = tid & 63;
    const int bid  = blockIdx.x;
    const int bw   = ((bid & 7) * 300 + (bid >> 3)) * PPB + w;   // XCD-bijective

    for (int i = tid; i < Hh * LL + 32; i += TPB)
        sPEA[i] = (i < Hh * LL) ? ws[WS_PEA + i] : ws[WS_AC + (i - Hh * LL)];
    __syncthreads();
    const float* sAC = sPEA + Hh * LL;

    char* A = smem[w];
    int*                hist4 = (int*)A;                      // [4][260]
    _Float16*           attnh = (_Float16*)A;                 // [8][104] (after select)
    unsigned long long* list  = (unsigned long long*)(A + AR_LIST);
    int*                sel   = (int*)(A + AR_SEL);
    unsigned char*      perm  = (unsigned char*)(A + AR_PERM);
    float*              smk   = (float*)(A + AR_SMK);
    float*              feat3 = (float*)(A + AR_F3);
    float*              coefA = (float*)(A + AR_COEF);

    const float* distRow = dist + (size_t)bw * Nn;
    const float* maskRow = ninf + (size_t)bw * Nn;
    const float* xyRow   = xy   + (size_t)bw * Nn * 2;
    const float* demRow  = ndem + (size_t)bw * Nn;

    // ---- phase 0: stream dist+mask (coalesced float4), mask kept in regs
    float dvf[16], mkf[16];
    {
        float4 dv[4], mv[4];
        #pragma unroll
        for (int c = 0; c < 4; ++c) {
            int n0 = c * 256 + lane * 4;
            if (n0 < Nn) {
                dv[c] = *(const float4*)(distRow + n0);
                mv[c] = *(const float4*)(maskRow + n0);
            } else {
                dv[c] = make_float4(0.f, 0.f, 0.f, 0.f);
                mv[c] = make_float4(0.f, 0.f, 0.f, 0.f);
            }
        }
        #pragma unroll
        for (int k = 0; k < 5; ++k) {
            int idx = lane + 64 * k;
            if (idx < 260) ((int4*)hist4)[idx] = make_int4(0, 0, 0, 0);
        }
        #pragma unroll
        for (int c = 0; c < 4; ++c) {
            dvf[4*c+0] = dv[c].x; dvf[4*c+1] = dv[c].y; dvf[4*c+2] = dv[c].z; dvf[4*c+3] = dv[c].w;
            mkf[4*c+0] = mv[c].x; mkf[4*c+1] = mv[c].y; mkf[4*c+2] = mv[c].z; mkf[4*c+3] = mv[c].w;
        }
    }
    unsigned long long rk[16];
    #pragma unroll
    for (int r = 0; r < 16; ++r) {
        int n = (r >> 2) * 256 + lane * 4 + (r & 3);
        unsigned long long kv = ~0ull;
        if (n >= 1 && n < Nn) {
            float de = dvf[r] - mkf[r];
            kv = ((unsigned long long)f2key(de) << 32) | (unsigned)n;
        }
        rk[r] = kv;
    }
    WSYNC();

    // ---- radix select (MSB-first, 4 bank-staggered sub-hists), wave-local
    unsigned long long prefix = 0;
    int shift = 56;
    int remRank = 99;
    const unsigned long long ltm = (1ull << lane) - 1ull;
    const int g0 = (lane >> 4) * 260;
    for (int round = 0; round < 8; ++round) {
        shift = 56 - 8 * round;
        #pragma unroll
        for (int r = 0; r < 16; ++r) {
            unsigned long long kv = rk[r];
            bool in = (kv != ~0ull) &&
                      (round == 0 || (kv >> (shift + 8)) == (prefix >> (shift + 8)));
            if (in) atomicAdd(&hist4[g0 + (int)((kv >> shift) & 0xffull)], 1);
        }
        WSYNC();
        int4 h0 = *(int4*)&hist4[0 * 260 + 4 * lane];
        int4 h1 = *(int4*)&hist4[1 * 260 + 4 * lane];
        int4 h2 = *(int4*)&hist4[2 * 260 + 4 * lane];
        int4 h3 = *(int4*)&hist4[3 * 260 + 4 * lane];
        int4 z = make_int4(0, 0, 0, 0);
        *(int4*)&hist4[0 * 260 + 4 * lane] = z;
        *(int4*)&hist4[1 * 260 + 4 * lane] = z;
        *(int4*)&hist4[2 * 260 + 4 * lane] = z;
        *(int4*)&hist4[3 * 260 + 4 * lane] = z;
        int cx = h0.x + h1.x + h2.x + h3.x;
        int cy = h0.y + h1.y + h2.y + h3.y;
        int cz = h0.z + h1.z + h2.z + h3.z;
        int cw = h0.w + h1.w + h2.w + h3.w;
        int s = cx + cy + cz + cw;
        int incl = s;
        #pragma unroll
        for (int o = 1; o < 64; o <<= 1) { int t = __shfl_up(incl, o, 64); if (lane >= o) incl += t; }
        int e0 = incl - s;
        int e1 = e0 + cx, e2 = e1 + cy, e3 = e2 + cz;
        int bc = -1, ec = 0, cc = 0;
        if (cx > 0 && remRank >= e0 && remRank < e1)      { bc = 4*lane+0; ec = e0; cc = cx; }
        if (cy > 0 && remRank >= e1 && remRank < e2)      { bc = 4*lane+1; ec = e1; cc = cy; }
        if (cz > 0 && remRank >= e2 && remRank < e3)      { bc = 4*lane+2; ec = e2; cc = cz; }
        if (cw > 0 && remRank >= e3 && remRank < e3 + cw) { bc = 4*lane+3; ec = e3; cc = cw; }
        unsigned long long fm = __ballot(bc >= 0);
        int srcl = __ffsll((unsigned long long)fm) - 1;
        bc = __shfl(bc, srcl, 64); ec = __shfl(ec, srcl, 64); cc = __shfl(cc, srcl, 64);
        prefix |= ((unsigned long long)(unsigned)bc) << shift;
        remRank -= ec;
        if (cc == 1) break;
    }
    unsigned long long pk = 0; bool pf = false;
    #pragma unroll
    for (int r = 0; r < 16; ++r)
        if ((rk[r] >> shift) == (prefix >> shift)) { pk = rk[r]; pf = true; }
    {
        unsigned long long fm = __ballot(pf);
        int srcl = __ffsll((unsigned long long)fm) - 1;
        pk = __shfl(pk, srcl, 64);
    }
    const unsigned long long pivot = pk;

    // ---- ballot-compact the 100 keys <= pivot into list (p-order)
    int cnt_run = 0;
    #pragma unroll
    for (int r = 0; r < 16; ++r) {
        bool p = rk[r] <= pivot;
        unsigned long long m = __ballot(p);
        if (p) list[cnt_run + (int)__popcll(m & ltm)] = rk[r];
        cnt_run += (int)__popcll(m);
    }
    WSYNC();

    // ---- issue xy/ndem streams NOW (latency hides under the rank loop)
    float xs[16], ys[16], dd[16];
    {
        #pragma unroll
        for (int c = 0; c < 4; ++c) {
            int n0 = c * 256 + lane * 4;
            float4 a0, a1, d0;
            if (n0 < Nn) {
                a0 = *(const float4*)(xyRow + 2 * n0);
                a1 = *(const float4*)(xyRow + 2 * n0 + 4);
                d0 = *(const float4*)(demRow + n0);
            } else {
                a0 = a1 = d0 = make_float4(0.f, 0.f, 0.f, 0.f);
            }
            xs[4*c+0] = a0.x; ys[4*c+0] = a0.y;
            xs[4*c+1] = a0.z; ys[4*c+1] = a0.w;
            xs[4*c+2] = a1.x; ys[4*c+2] = a1.y;
            xs[4*c+3] = a1.z; ys[4*c+3] = a1.w;
            dd[4*c+0] = d0.x; dd[4*c+1] = d0.y; dd[4*c+2] = d0.z; dd[4*c+3] = d0.w;
        }
    }

    // ---- parallel rank: perm[p] = rank+1 ; norm max
    {
        unsigned long long kv0 = list[lane];
        const bool has1 = lane < (LOCALK - 64);
        unsigned long long kv1 = has1 ? list[lane + 64] : ~0ull;
        int r0 = 0, r1 = 0;
        #pragma unroll 4
        for (int j = 0; j < LOCALK; ++j) {
            unsigned long long lv = list[j];
            r0 += (lv < kv0);
            r1 += (lv < kv1);
        }
        float v0 = key2f((unsigned)(kv0 >> 32));
        float dvm = isinf(v0) ? 0.f : v0;
        perm[lane] = (unsigned char)(r0 + 1);
        if (has1) {
            float v1 = key2f((unsigned)(kv1 >> 32));
            perm[lane + 64] = (unsigned char)(r1 + 1);
            dvm = fmaxf(dvm, isinf(v1) ? 0.f : v1);
        }
        #pragma unroll
        for (int o = 32; o > 0; o >>= 1) dvm = fmaxf(dvm, __shfl_xor(dvm, o, 64));
        const float nmax = dvm;
        const bool  norm_on = (nmax != 0.f);
        const float nfac = nmax + 1e-6f;
        WSYNC();

        // ---- scatter features from registers (no global gather)
        int crun = 0;
        #pragma unroll
        for (int r = 0; r < 16; ++r) {
            unsigned long long kv = rk[r];
            bool p = kv <= pivot;
            unsigned long long m = __ballot(p);
            int pos = crun + (int)__popcll(m & ltm);
            crun += (int)__popcll(m);
            if (p) {
                int rnk = perm[pos];
                float val = key2f((unsigned)(kv >> 32));
                bool infm = isinf(val);
                float fx = infm ? 0.f : xs[r];
                float fy = infm ? 0.f : ys[r];
                float fd = infm ? 0.f : dd[r];
                if (norm_on) { fx /= nfac; fy /= nfac; }
                int n = (int)(kv & 0xffffffu);
                feat3[rnk] = fx; feat3[101 + rnk] = fy; feat3[202 + rnk] = fd;
                smk[rnk] = mkf[r];
                sel[rnk] = n | (infm ? 0x4000 : 0);
            }
        }
        if (lane == 0) {
            feat3[0] = 0.f; feat3[101] = 0.f; feat3[202] = 0.f; feat3[303] = 0.f;
            smk[0] = mkf[0];
            sel[0] = 0x4000;
            sel[101] = 0; sel[102] = 0; sel[103] = 0;
        }
    }
    WSYNC();

    // ---- fused scores + softmax + coef: 8 lanes per head
    const int h = lane >> 3, ln8 = lane & 7;
    {
        const float A0 = sAC[h], A1 = sAC[8 + h], A2 = sAC[16 + h], Cc = sAC[24 + h];
        const float* pea = sPEA + h * LL;
        float ev[13];
        float mx = -INFINITY;
        #pragma unroll
        for (int k = 0; k < 13; ++k) {
            int l = ln8 + 8 * k;
            float sv = -INFINITY;
            if (l < LL)
                sv = feat3[l] * A0 + feat3[101 + l] * A1 + feat3[202 + l] * A2
                   + Cc + pea[l] + smk[l];
            ev[k] = sv;
            mx = fmaxf(mx, sv);
        }
        #pragma unroll
        for (int o = 1; o < 8; o <<= 1) mx = fmaxf(mx, __shfl_xor(mx, o, 64));
        float sm = 0.f;
        #pragma unroll
        for (int k = 0; k < 13; ++k) {
            int l = ln8 + 8 * k;
            float e = (l < LL) ? __expf(ev[k] - mx) : 0.f;
            ev[k] = e; sm += e;
        }
        #pragma unroll
        for (int o = 1; o < 8; o <<= 1) sm += __shfl_xor(sm, o, 64);
        const float ainv = 1.f / sm;
        float c0 = 0.f, c1 = 0.f, c2 = 0.f;
        #pragma unroll
        for (int k = 0; k < 13; ++k) {
            int l = ln8 + 8 * k;                 // l <= 103
            float at = ev[k] * ainv;
            attnh[h * 104 + l] = (_Float16)at;   // zeros at 101..103
            if (l < LL) {
                c0 += at * feat3[l]; c1 += at * feat3[101 + l]; c2 += at * feat3[202 + l];
            }
        }
        #pragma unroll
        for (int o = 1; o < 8; o <<= 1) {
            c0 += __shfl_xor(c0, o, 64); c1 += __shfl_xor(c1, o, 64); c2 += __shfl_xor(c2, o, 64);
        }
        if (ln8 == 0) { coefA[h * 3 + 0] = c0; coefA[h * 3 + 1] = c1; coefA[h * 3 + 2] = c2; }
    }
    WSYNC();

    // ---- staging copy to this problem's out row (coalesced 16B stores)
    {
        float* gRow = out + (size_t)bw * Nn;
        // attn: 104 x 16B
        ((int4*)gRow)[lane] = ((const int4*)attnh)[lane];
        if (lane < 40) ((int4*)gRow)[lane + 64] = ((const int4*)attnh)[lane + 64];
        // feat f16: 38 x 16B
        if (lane < 38) {
            int c = lane;
            int wd[4];
            #pragma unroll
            for (int k2 = 0; k2 < 4; ++k2) {
                unsigned lo = f2hbits(feat3[8 * c + 2 * k2]);
                unsigned hi = f2hbits(feat3[8 * c + 2 * k2 + 1]);
                wd[k2] = (int)(lo | (hi << 16));
            }
            ((int4*)(gRow + 416))[c] = make_int4(wd[0], wd[1], wd[2], wd[3]);
        }
        // sel u16: 13 x 16B
        if (lane < 13) {
            int c = lane;
            int wd[4];
            #pragma unroll
            for (int k2 = 0; k2 < 4; ++k2) {
                unsigned lo = (unsigned)sel[8 * c + 2 * k2] & 0xffffu;
                unsigned hi = (unsigned)sel[8 * c + 2 * k2 + 1] & 0xffffu;
                wd[k2] = (int)(lo | (hi << 16));
            }
            ((int4*)(gRow + 568))[c] = make_int4(wd[0], wd[1], wd[2], wd[3]);
        }
        // coef: 6 x 16B
        if (lane < 6) ((int4*)(gRow + 620))[lane] = ((const int4*)coefA)[lane];
    }
}

// ================= Kernel B: LDS-table matmuls + scatter + row write =================
#define BG 8   // problems per block
__global__ __launch_bounds__(256, 2) void kernelB(
    const float* __restrict__ ws,
    float* __restrict__ out) {

    __shared__ __align__(16) _Float16 PVL[LL * 132];     // PVT[l][hd], stride 132
    __shared__ __align__(16) _Float16 GPTL[EMB * 132];   // GPT[hd][l], stride 132
    __shared__ __align__(16) float wcc[620];             // WCW[512] | cb[4] | cbpe[104]
    __shared__ __align__(16) _Float16 attnL[832];
    __shared__ __align__(16) _Float16 f3h[304];
    __shared__ __align__(16) unsigned short selL[104];
    __shared__ __align__(16) float coefL[24];
    __shared__ __align__(16) float uf[EMB];
    __shared__ float cM[4];
    __shared__ __align__(16) float rowbuf[1000];

    const int tid = threadIdx.x;
    const int bid = blockIdx.x;
    const int gb  = (bid & 7) * 75 + (bid >> 3);   // 600 = 8*75, bijective
    const int p0  = gb * BG;

    // ---- stage tables once (8B chunks to handle stride-132 odd-row alignment)
    for (int c = tid; c < 3232; c += 256) {        // PVT: 12928 halves
        int hi = c * 4;
        int l = hi >> 7, col = hi & 127;
        *(int2*)(PVL + l * 132 + col) = ((const int2*)(ws + WS_PVT))[c];
    }
    for (int c = tid; c < 3328; c += 256) {        // GPT: 13312 halves
        int hi = c * 4;
        int hd = hi / 104, col = hi - hd * 104;
        *(int2*)(GPTL + hd * 132 + col) = ((const int2*)(ws + WS_GPT))[c];
    }
    for (int c = tid; c < 155; c += 256)
        ((int4*)wcc)[c] = ((const int4*)(ws + WS_WCW))[c];
    __syncthreads();

    for (int pp = 0; pp < BG; ++pp) {
        const int p = p0 + pp;
        float* gRow = out + (size_t)p * Nn;

        // ---- stage this problem's data (161 x 16B)
        for (int c = tid; c < 161; c += 256) {
            int4 v = ((const int4*)gRow)[c];
            if (c < 104)       ((int4*)attnL)[c] = v;
            else if (c < 142)  ((int4*)f3h)[c - 104] = v;
            else if (c < 155)  ((int4*)selL)[c - 142] = v;
            else               ((int4*)coefL)[c - 155] = v;
        }
        __syncthreads();

        // ---- u[hd] (threads 0..127) ; zero rowbuf (threads 128..255)
        if (tid < 128) {
            int t = tid, hh = t >> 4;
            const _Float16* arow = attnL + hh * 104;
            float acc = 0.f;
            #pragma unroll 4
            for (int l = 0; l < LL; ++l)
                acc += (float)arow[l] * (float)PVL[l * 132 + t];
            acc += coefL[hh * 3 + 0] * ws[WS_WVI + t]
                 + coefL[hh * 3 + 1] * ws[WS_WVI + 128 + t]
                 + coefL[hh * 3 + 2] * ws[WS_WVI + 256 + t]
                 + ws[WS_WVI + 384 + t];
            uf[t] = acc;
        } else {
            int z = tid - 128;
            f4v zero = {0.f, 0.f, 0.f, 0.f};
            #pragma unroll
            for (int k = 0; k < 2; ++k) {
                int i = z + 128 * k;
                if (i < 250) *(f4v*)(rowbuf + 4 * i) = zero;
            }
        }
        __syncthreads();

        // ---- coefM (wave 0)
        if (tid < 64) {
            #pragma unroll
            for (int i = 0; i < 4; ++i) {
                float v = uf[tid] * wcc[i * 128 + tid] + uf[tid + 64] * wcc[i * 128 + tid + 64];
                #pragma unroll
                for (int o = 32; o > 0; o >>= 1) v += __shfl_xor(v, o, 64);
                if (tid == 0) cM[i] = wcc[512 + i] + v;
            }
        }
        __syncthreads();

        // ---- score2 + scatter into rowbuf
        if (tid < LL) {
            int t = tid;
            float acc = 0.f;
            #pragma unroll 4
            for (int hd = 0; hd < EMB; ++hd)
                acc += uf[hd] * (float)GPTL[hd * 132 + t];
            float base = (float)f3h[t] * cM[0] + (float)f3h[101 + t] * cM[1]
                       + (float)f3h[202 + t] * cM[2] + cM[3] + wcc[516 + t];
            int n = (int)selL[t] & 0xFFF;
            rowbuf[n] = (base + acc) * 0.08838834764831845f;
        }
        __syncthreads();

        // ---- write the full row (coalesced, nontemporal)
        for (int c = tid; c < 250; c += 256) {
            f4v v = *(const f4v*)(rowbuf + 4 * c);
            __builtin_nontemporal_store(v, (f4v*)(gRow + 4 * c));
        }
        __syncthreads();
    }
}

extern "C" void kernel_launch(void* const* d_in, const int* in_sizes, int n_in,
                              void* d_out, int out_size, void* d_ws, size_t ws_size,
                              hipStream_t stream) {
    // 0 theta, 1 dist, 2 xy, 3 norm_demand, 4 ninf_mask,
    // 5 init_w, 6 init_b, 7 cur_token, 8 Wq, 9 Wk, 10 Wv, 11 Wc_w, 12 Wc_b
    const float* dist  = (const float*)d_in[1];
    const float* xy    = (const float*)d_in[2];
    const float* ndem  = (const float*)d_in[3];
    const float* ninf  = (const float*)d_in[4];
    const float* initw = (const float*)d_in[5];
    const float* initb = (const float*)d_in[6];
    const float* cur   = (const float*)d_in[7];
    const float* Wq    = (const float*)d_in[8];
    const float* Wk    = (const float*)d_in[9];
    const float* Wv    = (const float*)d_in[10];
    const float* Wcw   = (const float*)d_in[11];
    const float* Wcb   = (const float*)d_in[12];
    float* out = (float*)d_out;
    float* ws  = (float*)d_ws;

    hipLaunchKernelGGL(setup1, dim3(56),  dim3(256), 0, stream, cur, Wq, Wk, initw, initb, Wv, ws);
    hipLaunchKernelGGL(setup2, dim3(109), dim3(256), 0, stream, Wv, Wcw, Wcb, initw, initb, ws);
    hipLaunchKernelGGL(kernelA, dim3(Bb * Ww / PPB), dim3(TPB), 0, stream,
                       dist, xy, ndem, ninf, ws, out);
    hipLaunchKernelGGL(kernelB, dim3(Bb * Ww / BG), dim3(256), 0, stream, ws, out);
}

// Round 12
// 108.739 us; speedup vs baseline: 1.7916x; 1.7916x over previous
//
#include <hip/hip_runtime.h>
#include <math.h>

#define Bb   48
#define Ww   100
#define Nn   1000
#define EMB  128
#define Hh   8
#define LL   101     // depot + 100 neighbors
#define LOCALK 100
#define TPB  128
#define PPB  2       // problems (waves) per block in kernel A

typedef float f4v __attribute__((ext_vector_type(4)));

// ---- workspace layout (float offsets)
#define WS_A     0       // [8][128]  a_h = (Wk q_h)/4
#define WS_PE    1024    // [101][128] pos-enc f32
#define WS_AC    13952   // [3][8] A_i[h] then [8] C[h]
#define WS_WVI   13984   // [4][128]  w_i·Wv[:,hd] (i=3 -> b)
#define WS_PEA   14496   // [8][101]  pe[l]·a_h
#define WS_PVT   15304   // f16 [101][128]  PVT[l][hd] = pe[l]·Wv[:,hd]
#define WS_GPT   21768   // f16 [128][104]  GPT[hd][l] = Wcw[hd]·pe[l], l>=101 -> 0
#define WS_WCW   28424   // f32 [4][128]  Wcw·w_i  (i=3 -> b)
#define WS_CB    28936   // f32 [4]       Wcb·w_i
#define WS_CBPE  28940   // f32 [104]     Wcb·pe[l]
// end 29044 floats = 116 KB

// ---- kernel A per-problem LDS arena (bytes), regions time-multiplexed
#define AR_SIZE 7360
#define AR_LIST 4288     // u64[100]
#define AR_SEL  5088     // i32[104]  (node | 0x4000 inf-flag; pad 101..103 = 0)
#define AR_PERM 5504     // u8[104]
#define AR_SMK  5616     // f32[101]
#define AR_F3   6032     // f32[304]  (pad [303] = 0)
#define AR_COEF 7248     // f32[24]

// staging layout inside each out row (f32 slots):
//  [0..415]   attn f16[8][104]
//  [416..567] feat f16[304]
//  [568..619] sel  u16[104]
//  [620..643] coef f32[24]

#define WSYNC() do { __builtin_amdgcn_wave_barrier(); asm volatile("" ::: "memory"); } while (0)

__device__ __forceinline__ unsigned f2key(float x) {
    unsigned u = __float_as_uint(x);
    return (u & 0x80000000u) ? ~u : (u | 0x80000000u);
}
__device__ __forceinline__ float key2f(unsigned k) {
    unsigned u = (k & 0x80000000u) ? (k & 0x7fffffffu) : ~k;
    return __uint_as_float(u);
}
__device__ __forceinline__ unsigned short f2hbits(float x) {
    union { _Float16 h; unsigned short u; } cv;
    cv.h = (_Float16)x;
    return cv.u;
}

// ---- S1: q, a, A/C (block 0); pe + WVi (blocks 1..)
__global__ void setup1(const float* __restrict__ cur, const float* __restrict__ Wq,
                       const float* __restrict__ Wk, const float* __restrict__ iw,
                       const float* __restrict__ ib, const float* __restrict__ Wv,
                       float* __restrict__ ws) {
    const int t = threadIdx.x, b = blockIdx.x;
    if (b == 0) {
        __shared__ float qs[EMB];
        __shared__ float as_[Hh * EMB];
        if (t < EMB) {
            float acc = 0.f;
            for (int e = 0; e < EMB; ++e) acc += cur[e] * Wq[e * EMB + t];
            qs[t] = acc;
        }
        __syncthreads();
        for (int i = t; i < Hh * EMB; i += 256) {
            int h = i >> 7, e = i & 127;
            float acc = 0.f;
            for (int d = 0; d < 16; ++d) acc += Wk[e * EMB + h * 16 + d] * qs[h * 16 + d];
            acc *= 0.25f;
            as_[i] = acc; ws[WS_A + i] = acc;
        }
        __syncthreads();
        if (t < 32) {
            int i = t >> 3, h = t & 7;
            const float* src = (i == 0) ? iw : (i == 1) ? iw + EMB : (i == 2) ? iw + 2 * EMB : ib;
            float acc = 0.f;
            for (int e = 0; e < EMB; ++e) acc += src[e] * as_[h * EMB + e];
            ws[WS_AC + t] = acc;
        }
    } else {
        int base = (b - 1) * 256 + t;
        const float kneg = -0.14619587891040738f;  // -ln(10000)/63
        if (base < LL * EMB) {
            int l = base >> 7, c = base & 127, ic = c & 63;
            float inv = expf((float)ic * kneg);
            float v = (float)l * inv;
            ws[WS_PE + base] = (c < 64) ? sinf(v) : cosf(v);
        } else if (base < LL * EMB + 512) {
            int j = base - LL * EMB;
            int iv = j >> 7, hd = j & 127;
            const float* src = (iv == 0) ? iw : (iv == 1) ? iw + EMB : (iv == 2) ? iw + 2 * EMB : ib;
            float acc = 0.f;
            for (int e = 0; e < EMB; ++e) acc += src[e] * Wv[e * EMB + hd];
            ws[WS_WVI + j] = acc;
        }
    }
}

// ---- S2: PVT f16, GPT f16, PEA, WCW, cb, cbpe  (reads ws PE/A from setup1)
__global__ void setup2(const float* __restrict__ Wv, const float* __restrict__ Wcw,
                       const float* __restrict__ Wcb, const float* __restrict__ iw,
                       const float* __restrict__ ib, float* __restrict__ ws) {
    int idx = blockIdx.x * 256 + threadIdx.x;
    if (idx < 12928) {                               // PVT[l][hd]
        int l = idx >> 7, hd = idx & 127;
        const float* pr = ws + WS_PE + l * EMB;
        float acc = 0.f;
        for (int e = 0; e < EMB; ++e) acc += pr[e] * Wv[e * EMB + hd];
        ((_Float16*)(ws + WS_PVT))[idx] = (_Float16)acc;
    } else if (idx < 12928 + 13312) {                // GPT[hd][l]
        int j = idx - 12928;
        int hd = j / 104, l = j - hd * 104;
        float acc = 0.f;
        if (l < LL) {
            const float* wr = Wcw + hd * EMB;
            const float* pr = ws + WS_PE + l * EMB;
            for (int e = 0; e < EMB; ++e) acc += wr[e] * pr[e];
        }
        ((_Float16*)(ws + WS_GPT))[j] = (_Float16)acc;
    } else if (idx < 26240 + 808) {                  // PEA[h][l]
        int j = idx - 26240;
        int h = j / LL, l = j - h * LL;
        const float* pr = ws + WS_PE + l * EMB;
        const float* ar = ws + WS_A + h * EMB;
        float acc = 0.f;
        for (int e = 0; e < EMB; ++e) acc += pr[e] * ar[e];
        ws[WS_PEA + j] = acc;
    } else if (idx < 27048 + 512) {                  // WCW[i][hd]
        int j = idx - 27048;
        int i = j >> 7, hd = j & 127;
        const float* src = (i == 0) ? iw : (i == 1) ? iw + EMB : (i == 2) ? iw + 2 * EMB : ib;
        const float* wr = Wcw + hd * EMB;
        float acc = 0.f;
        for (int e = 0; e < EMB; ++e) acc += wr[e] * src[e];
        ws[WS_WCW + j] = acc;
    } else if (idx < 27560 + 4) {                    // cb[i]
        int i = idx - 27560;
        const float* src = (i == 0) ? iw : (i == 1) ? iw + EMB : (i == 2) ? iw + 2 * EMB : ib;
        float acc = 0.f;
        for (int e = 0; e < EMB; ++e) acc += Wcb[e] * src[e];
        ws[WS_CB + i] = acc;
    } else if (idx < 27564 + 104) {                  // cbpe[l]
        int l = idx - 27564;
        float acc = 0.f;
        if (l < LL) {
            const float* pr = ws + WS_PE + l * EMB;
            for (int e = 0; e < EMB; ++e) acc += Wcb[e] * pr[e];
        }
        ws[WS_CBPE + l] = acc;
    }
}

// ================= Kernel A: select + features + attn + coef -> staging =================
__global__ __launch_bounds__(TPB, 6) void kernelA(
    const float* __restrict__ dist,
    const float* __restrict__ xy,
    const float* __restrict__ ndem,
    const float* __restrict__ ninf,
    const float* __restrict__ ws,
    float* __restrict__ out) {

    __shared__ __align__(16) char smem[PPB][AR_SIZE];
    __shared__ __align__(16) float sPEA[Hh * LL + 32];

    const int tid  = threadIdx.x;
    const int w    = tid >> 6;
    const int lane = tid & 63;
    const int bid  = blockIdx.x;
    const int bw   = ((bid & 7) * 300 + (bid >> 3)) * PPB + w;   // XCD-bijective

    for (int i = tid; i < Hh * LL + 32; i += TPB)
        sPEA[i] = (i < Hh * LL) ? ws[WS_PEA + i] : ws[WS_AC + (i - Hh * LL)];
    __syncthreads();
    const float* sAC = sPEA + Hh * LL;

    char* A = smem[w];
    int*                hist4 = (int*)A;                      // [4][260]
    _Float16*           attnh = (_Float16*)A;                 // [8][104] (after select)
    unsigned long long* list  = (unsigned long long*)(A + AR_LIST);
    int*                sel   = (int*)(A + AR_SEL);
    unsigned char*      perm  = (unsigned char*)(A + AR_PERM);
    float*              smk   = (float*)(A + AR_SMK);
    float*              feat3 = (float*)(A + AR_F3);
    float*              coefA = (float*)(A + AR_COEF);

    const float* distRow = dist + (size_t)bw * Nn;
    const float* maskRow = ninf + (size_t)bw * Nn;
    const float* xyRow   = xy   + (size_t)bw * Nn * 2;
    const float* demRow  = ndem + (size_t)bw * Nn;

    // ---- phase 0: stream dist+mask (nontemporal float4), mask kept in regs
    float dvf[16], mkf[16];
    {
        f4v dv[4], mv[4];
        #pragma unroll
        for (int c = 0; c < 4; ++c) {
            int n0 = c * 256 + lane * 4;
            if (n0 < Nn) {
                dv[c] = __builtin_nontemporal_load((const f4v*)(distRow + n0));
                mv[c] = __builtin_nontemporal_load((const f4v*)(maskRow + n0));
            } else {
                dv[c] = (f4v){0.f, 0.f, 0.f, 0.f};
                mv[c] = (f4v){0.f, 0.f, 0.f, 0.f};
            }
        }
        #pragma unroll
        for (int k = 0; k < 5; ++k) {
            int idx = lane + 64 * k;
            if (idx < 260) ((int4*)hist4)[idx] = make_int4(0, 0, 0, 0);
        }
        #pragma unroll
        for (int c = 0; c < 4; ++c) {
            dvf[4*c+0] = dv[c].x; dvf[4*c+1] = dv[c].y; dvf[4*c+2] = dv[c].z; dvf[4*c+3] = dv[c].w;
            mkf[4*c+0] = mv[c].x; mkf[4*c+1] = mv[c].y; mkf[4*c+2] = mv[c].z; mkf[4*c+3] = mv[c].w;
        }
    }
    unsigned long long rk[16];
    #pragma unroll
    for (int r = 0; r < 16; ++r) {
        int n = (r >> 2) * 256 + lane * 4 + (r & 3);
        unsigned long long kv = ~0ull;
        if (n >= 1 && n < Nn) {
            float de = dvf[r] - mkf[r];
            kv = ((unsigned long long)f2key(de) << 32) | (unsigned)n;
        }
        rk[r] = kv;
    }
    WSYNC();

    // ---- radix select (MSB-first, 4 bank-staggered sub-hists), wave-local
    unsigned long long prefix = 0;
    int shift = 56;
    int remRank = 99;
    const unsigned long long ltm = (1ull << lane) - 1ull;
    const int g0 = (lane >> 4) * 260;
    for (int round = 0; round < 8; ++round) {
        shift = 56 - 8 * round;
        #pragma unroll
        for (int r = 0; r < 16; ++r) {
            unsigned long long kv = rk[r];
            bool in = (kv != ~0ull) &&
                      (round == 0 || (kv >> (shift + 8)) == (prefix >> (shift + 8)));
            if (in) atomicAdd(&hist4[g0 + (int)((kv >> shift) & 0xffull)], 1);
        }
        WSYNC();
        int4 h0 = *(int4*)&hist4[0 * 260 + 4 * lane];
        int4 h1 = *(int4*)&hist4[1 * 260 + 4 * lane];
        int4 h2 = *(int4*)&hist4[2 * 260 + 4 * lane];
        int4 h3 = *(int4*)&hist4[3 * 260 + 4 * lane];
        int4 z = make_int4(0, 0, 0, 0);
        *(int4*)&hist4[0 * 260 + 4 * lane] = z;
        *(int4*)&hist4[1 * 260 + 4 * lane] = z;
        *(int4*)&hist4[2 * 260 + 4 * lane] = z;
        *(int4*)&hist4[3 * 260 + 4 * lane] = z;
        int cx = h0.x + h1.x + h2.x + h3.x;
        int cy = h0.y + h1.y + h2.y + h3.y;
        int cz = h0.z + h1.z + h2.z + h3.z;
        int cw = h0.w + h1.w + h2.w + h3.w;
        int s = cx + cy + cz + cw;
        int incl = s;
        #pragma unroll
        for (int o = 1; o < 64; o <<= 1) { int t = __shfl_up(incl, o, 64); if (lane >= o) incl += t; }
        int e0 = incl - s;
        int e1 = e0 + cx, e2 = e1 + cy, e3 = e2 + cz;
        int bc = -1, ec = 0, cc = 0;
        if (cx > 0 && remRank >= e0 && remRank < e1)      { bc = 4*lane+0; ec = e0; cc = cx; }
        if (cy > 0 && remRank >= e1 && remRank < e2)      { bc = 4*lane+1; ec = e1; cc = cy; }
        if (cz > 0 && remRank >= e2 && remRank < e3)      { bc = 4*lane+2; ec = e2; cc = cz; }
        if (cw > 0 && remRank >= e3 && remRank < e3 + cw) { bc = 4*lane+3; ec = e3; cc = cw; }
        unsigned long long fm = __ballot(bc >= 0);
        int srcl = __ffsll((unsigned long long)fm) - 1;
        bc = __shfl(bc, srcl, 64); ec = __shfl(ec, srcl, 64); cc = __shfl(cc, srcl, 64);
        prefix |= ((unsigned long long)(unsigned)bc) << shift;
        remRank -= ec;
        if (cc == 1) break;
    }
    unsigned long long pk = 0; bool pf = false;
    #pragma unroll
    for (int r = 0; r < 16; ++r)
        if ((rk[r] >> shift) == (prefix >> shift)) { pk = rk[r]; pf = true; }
    {
        unsigned long long fm = __ballot(pf);
        int srcl = __ffsll((unsigned long long)fm) - 1;
        pk = __shfl(pk, srcl, 64);
    }
    const unsigned long long pivot = pk;

    // ---- ballot-compact the 100 keys <= pivot into list (p-order)
    int cnt_run = 0;
    #pragma unroll
    for (int r = 0; r < 16; ++r) {
        bool p = rk[r] <= pivot;
        unsigned long long m = __ballot(p);
        if (p) list[cnt_run + (int)__popcll(m & ltm)] = rk[r];
        cnt_run += (int)__popcll(m);
    }
    WSYNC();

    // ---- issue xy/ndem streams NOW (latency hides under the rank loop)
    float xs[16], ys[16], dd[16];
    {
        #pragma unroll
        for (int c = 0; c < 4; ++c) {
            int n0 = c * 256 + lane * 4;
            f4v a0, a1, d0;
            if (n0 < Nn) {
                a0 = __builtin_nontemporal_load((const f4v*)(xyRow + 2 * n0));
                a1 = __builtin_nontemporal_load((const f4v*)(xyRow + 2 * n0 + 4));
                d0 = __builtin_nontemporal_load((const f4v*)(demRow + n0));
            } else {
                a0 = a1 = d0 = (f4v){0.f, 0.f, 0.f, 0.f};
            }
            xs[4*c+0] = a0.x; ys[4*c+0] = a0.y;
            xs[4*c+1] = a0.z; ys[4*c+1] = a0.w;
            xs[4*c+2] = a1.x; ys[4*c+2] = a1.y;
            xs[4*c+3] = a1.z; ys[4*c+3] = a1.w;
            dd[4*c+0] = d0.x; dd[4*c+1] = d0.y; dd[4*c+2] = d0.z; dd[4*c+3] = d0.w;
        }
    }

    // ---- parallel rank: perm[p] = rank+1 ; norm max
    {
        unsigned long long kv0 = list[lane];
        const bool has1 = lane < (LOCALK - 64);
        unsigned long long kv1 = has1 ? list[lane + 64] : ~0ull;
        int r0 = 0, r1 = 0;
        #pragma unroll 4
        for (int j = 0; j < LOCALK; ++j) {
            unsigned long long lv = list[j];
            r0 += (lv < kv0);
            r1 += (lv < kv1);
        }
        float v0 = key2f((unsigned)(kv0 >> 32));
        float dvm = isinf(v0) ? 0.f : v0;
        perm[lane] = (unsigned char)(r0 + 1);
        if (has1) {
            float v1 = key2f((unsigned)(kv1 >> 32));
            perm[lane + 64] = (unsigned char)(r1 + 1);
            dvm = fmaxf(dvm, isinf(v1) ? 0.f : v1);
        }
        #pragma unroll
        for (int o = 32; o > 0; o >>= 1) dvm = fmaxf(dvm, __shfl_xor(dvm, o, 64));
        const float nmax = dvm;
        const bool  norm_on = (nmax != 0.f);
        const float nfac = nmax + 1e-6f;
        WSYNC();

        // ---- scatter features from registers (no global gather)
        int crun = 0;
        #pragma unroll
        for (int r = 0; r < 16; ++r) {
            unsigned long long kv = rk[r];
            bool p = kv <= pivot;
            unsigned long long m = __ballot(p);
            int pos = crun + (int)__popcll(m & ltm);
            crun += (int)__popcll(m);
            if (p) {
                int rnk = perm[pos];
                float val = key2f((unsigned)(kv >> 32));
                bool infm = isinf(val);
                float fx = infm ? 0.f : xs[r];
                float fy = infm ? 0.f : ys[r];
                float fd = infm ? 0.f : dd[r];
                if (norm_on) { fx /= nfac; fy /= nfac; }
                int n = (int)(kv & 0xffffffu);
                feat3[rnk] = fx; feat3[101 + rnk] = fy; feat3[202 + rnk] = fd;
                smk[rnk] = mkf[r];
                sel[rnk] = n | (infm ? 0x4000 : 0);
            }
        }
        if (lane == 0) {
            feat3[0] = 0.f; feat3[101] = 0.f; feat3[202] = 0.f; feat3[303] = 0.f;
            smk[0] = mkf[0];
            sel[0] = 0x4000;
            sel[101] = 0; sel[102] = 0; sel[103] = 0;
        }
    }
    WSYNC();

    // ---- fused scores + softmax + coef: 8 lanes per head
    const int h = lane >> 3, ln8 = lane & 7;
    {
        const float A0 = sAC[h], A1 = sAC[8 + h], A2 = sAC[16 + h], Cc = sAC[24 + h];
        const float* pea = sPEA + h * LL;
        float ev[13];
        float mx = -INFINITY;
        #pragma unroll
        for (int k = 0; k < 13; ++k) {
            int l = ln8 + 8 * k;
            float sv = -INFINITY;
            if (l < LL)
                sv = feat3[l] * A0 + feat3[101 + l] * A1 + feat3[202 + l] * A2
                   + Cc + pea[l] + smk[l];
            ev[k] = sv;
            mx = fmaxf(mx, sv);
        }
        #pragma unroll
        for (int o = 1; o < 8; o <<= 1) mx = fmaxf(mx, __shfl_xor(mx, o, 64));
        float sm = 0.f;
        #pragma unroll
        for (int k = 0; k < 13; ++k) {
            int l = ln8 + 8 * k;
            float e = (l < LL) ? __expf(ev[k] - mx) : 0.f;
            ev[k] = e; sm += e;
        }
        #pragma unroll
        for (int o = 1; o < 8; o <<= 1) sm += __shfl_xor(sm, o, 64);
        const float ainv = 1.f / sm;
        float c0 = 0.f, c1 = 0.f, c2 = 0.f;
        #pragma unroll
        for (int k = 0; k < 13; ++k) {
            int l = ln8 + 8 * k;                 // l <= 103
            float at = ev[k] * ainv;
            attnh[h * 104 + l] = (_Float16)at;   // zeros at 101..103
            if (l < LL) {
                c0 += at * feat3[l]; c1 += at * feat3[101 + l]; c2 += at * feat3[202 + l];
            }
        }
        #pragma unroll
        for (int o = 1; o < 8; o <<= 1) {
            c0 += __shfl_xor(c0, o, 64); c1 += __shfl_xor(c1, o, 64); c2 += __shfl_xor(c2, o, 64);
        }
        if (ln8 == 0) { coefA[h * 3 + 0] = c0; coefA[h * 3 + 1] = c1; coefA[h * 3 + 2] = c2; }
    }
    WSYNC();

    // ---- staging copy to this problem's out row (coalesced 16B stores)
    {
        float* gRow = out + (size_t)bw * Nn;
        // attn: 104 x 16B
        ((int4*)gRow)[lane] = ((const int4*)attnh)[lane];
        if (lane < 40) ((int4*)gRow)[lane + 64] = ((const int4*)attnh)[lane + 64];
        // feat f16: 38 x 16B
        if (lane < 38) {
            int c = lane;
            int wd[4];
            #pragma unroll
            for (int k2 = 0; k2 < 4; ++k2) {
                unsigned lo = f2hbits(feat3[8 * c + 2 * k2]);
                unsigned hi = f2hbits(feat3[8 * c + 2 * k2 + 1]);
                wd[k2] = (int)(lo | (hi << 16));
            }
            ((int4*)(gRow + 416))[c] = make_int4(wd[0], wd[1], wd[2], wd[3]);
        }
        // sel u16: 13 x 16B
        if (lane < 13) {
            int c = lane;
            int wd[4];
            #pragma unroll
            for (int k2 = 0; k2 < 4; ++k2) {
                unsigned lo = (unsigned)sel[8 * c + 2 * k2] & 0xffffu;
                unsigned hi = (unsigned)sel[8 * c + 2 * k2 + 1] & 0xffffu;
                wd[k2] = (int)(lo | (hi << 16));
            }
            ((int4*)(gRow + 568))[c] = make_int4(wd[0], wd[1], wd[2], wd[3]);
        }
        // coef: 6 x 16B
        if (lane < 6) ((int4*)(gRow + 620))[lane] = ((const int4*)coefA)[lane];
    }
}

// ================= Kernel B v2: 2 problems concurrent per block, LDS tables =================
#define BPB 2
__global__ __launch_bounds__(256, 2) void kernelB(
    const float* __restrict__ ws,
    float* __restrict__ out) {

    __shared__ __align__(16) _Float16 PVL[LL * 132];     // 26664 B
    __shared__ __align__(16) _Float16 GPTL[EMB * 132];   // 33792 B
    __shared__ __align__(16) float wcc[620];             // WCW[512] | cb[4] | cbpe[104]
    __shared__ __align__(16) _Float16 attnL[BPB][832];
    __shared__ __align__(16) _Float16 f3h[BPB][304];
    __shared__ __align__(16) unsigned short selL[BPB][104];
    __shared__ __align__(16) float coefL[BPB][24];
    __shared__ __align__(16) float uf[BPB][EMB];
    __shared__ float cM[BPB][4];
    __shared__ __align__(16) float rowbuf[BPB][1000];

    const int tid = threadIdx.x;
    const int sub = tid >> 7;        // which problem half-block
    const int t   = tid & 127;
    const int bid = blockIdx.x;
    const int gb  = (bid & 7) * 300 + (bid >> 3);   // 2400 = 8*300, bijective
    const int p   = gb * BPB + sub;
    float* gRow = out + (size_t)p * Nn;

    // ---- stage tables (whole block, once)
    for (int c = tid; c < 3232; c += 256) {        // PVT: 12928 halves
        int hi = c * 4;
        int l = hi >> 7, col = hi & 127;
        *(int2*)(PVL + l * 132 + col) = ((const int2*)(ws + WS_PVT))[c];
    }
    for (int c = tid; c < 3328; c += 256) {        // GPT: 13312 halves
        int hi = c * 4;
        int hd = hi / 104, col = hi - hd * 104;
        *(int2*)(GPTL + hd * 132 + col) = ((const int2*)(ws + WS_GPT))[c];
    }
    for (int c = tid; c < 155; c += 256)
        ((int4*)wcc)[c] = ((const int4*)(ws + WS_WCW))[c];

    // ---- stage this problem's data + zero rowbuf (sub-block local)
    for (int c = t; c < 161; c += 128) {
        int4 v = ((const int4*)gRow)[c];
        if (c < 104)       ((int4*)attnL[sub])[c] = v;
        else if (c < 142)  ((int4*)f3h[sub])[c - 104] = v;
        else if (c < 155)  ((int4*)selL[sub])[c - 142] = v;
        else               ((int4*)coefL[sub])[c - 155] = v;
    }
    {
        f4v z = {0.f, 0.f, 0.f, 0.f};
        for (int i = t; i < 250; i += 128) *(f4v*)(rowbuf[sub] + 4 * i) = z;
    }
    __syncthreads();

    // ---- u[hd] (each of 128 threads per sub-problem owns one hd)
    {
        int hh = t >> 4;
        const _Float16* arow = attnL[sub] + hh * 104;
        float acc = 0.f;
        #pragma unroll 4
        for (int l = 0; l < LL; ++l)
            acc += (float)arow[l] * (float)PVL[l * 132 + t];
        acc += coefL[sub][hh * 3 + 0] * ws[WS_WVI + t]
             + coefL[sub][hh * 3 + 1] * ws[WS_WVI + 128 + t]
             + coefL[sub][hh * 3 + 2] * ws[WS_WVI + 256 + t]
             + ws[WS_WVI + 384 + t];
        uf[sub][t] = acc;
    }
    __syncthreads();

    // ---- coefM (first wave of each sub-block)
    if (t < 64) {
        #pragma unroll
        for (int i = 0; i < 4; ++i) {
            float v = uf[sub][t] * wcc[i * 128 + t] + uf[sub][t + 64] * wcc[i * 128 + t + 64];
            #pragma unroll
            for (int o = 32; o > 0; o >>= 1) v += __shfl_xor(v, o, 64);
            if (t == 0) cM[sub][i] = wcc[512 + i] + v;
        }
    }
    __syncthreads();

    // ---- score2 + scatter into rowbuf
    if (t < LL) {
        float acc = 0.f;
        #pragma unroll 4
        for (int hd = 0; hd < EMB; ++hd)
            acc += uf[sub][hd] * (float)GPTL[hd * 132 + t];
        float base = (float)f3h[sub][t] * cM[sub][0] + (float)f3h[sub][101 + t] * cM[sub][1]
                   + (float)f3h[sub][202 + t] * cM[sub][2] + cM[sub][3] + wcc[516 + t];
        int n = (int)selL[sub][t] & 0xFFF;
        rowbuf[sub][n] = (base + acc) * 0.08838834764831845f;
    }
    __syncthreads();

    // ---- write the full row (coalesced, nontemporal)
    for (int c = t; c < 250; c += 128) {
        f4v v = *(const f4v*)(rowbuf[sub] + 4 * c);
        __builtin_nontemporal_store(v, (f4v*)(gRow + 4 * c));
    }
}

extern "C" void kernel_launch(void* const* d_in, const int* in_sizes, int n_in,
                              void* d_out, int out_size, void* d_ws, size_t ws_size,
                              hipStream_t stream) {
    // 0 theta, 1 dist, 2 xy, 3 norm_demand, 4 ninf_mask,
    // 5 init_w, 6 init_b, 7 cur_token, 8 Wq, 9 Wk, 10 Wv, 11 Wc_w, 12 Wc_b
    const float* dist  = (const float*)d_in[1];
    const float* xy    = (const float*)d_in[2];
    const float* ndem  = (const float*)d_in[3];
    const float* ninf  = (const float*)d_in[4];
    const float* initw = (const float*)d_in[5];
    const float* initb = (const float*)d_in[6];
    const float* cur   = (const float*)d_in[7];
    const float* Wq    = (const float*)d_in[8];
    const float* Wk    = (const float*)d_in[9];
    const float* Wv    = (const float*)d_in[10];
    const float* Wcw   = (const float*)d_in[11];
    const float* Wcb   = (const float*)d_in[12];
    float* out = (float*)d_out;
    float* ws  = (float*)d_ws;

    hipLaunchKernelGGL(setup1, dim3(56),  dim3(256), 0, stream, cur, Wq, Wk, initw, initb, Wv, ws);
    hipLaunchKernelGGL(setup2, dim3(109), dim3(256), 0, stream, Wv, Wcw, Wcb, initw, initb, ws);
    hipLaunchKernelGGL(kernelA, dim3(Bb * Ww / PPB), dim3(TPB), 0, stream,
                       dist, xy, ndem, ninf, ws, out);
    hipLaunchKernelGGL(kernelB, dim3(Bb * Ww / BPB), dim3(256), 0, stream, ws, out);
}